// Round 11
// baseline (17.780 us; speedup 1.0000x reference)
//
#include <hip/hip_runtime.h>
#include <math.h>

#define EPS 1e-8f
#define NPTS 24
#define MAXN_LDS 2048      // row kernel supports n <= 2048
#define CHUNKB 1024        // boxes staged per chunk (28KB raw)
#define ROWS 4             // rows per block
#define NREG 64            // fallback pipeline worklist regions
#define CTR_STRIDE 64

// ---- constexpr Batcher odd-even mergesort comparator network for NPTS=24 ----
struct Net {
    int n;
    unsigned char lo[256];
    unsigned char hi[256];
};
constexpr Net build_net() {
    Net net{};
    net.n = 0;
    for (int p = 1; p < NPTS; p <<= 1)
        for (int k = p; k >= 1; k >>= 1)
            for (int j = k % p; j + k < NPTS; j += 2 * k)
                for (int i = 0; i < k && i + j + k < NPTS; ++i)
                    if ((i + j) / (2 * p) == (i + j + k) / (2 * p)) {
                        net.lo[net.n] = (unsigned char)(i + j);
                        net.hi[net.n] = (unsigned char)(i + j + k);
                        ++net.n;
                    }
    return net;
}
constexpr Net NET = build_net();

// ---- verified heavy path: full sort of (key, px, py) ----
// Measured live set = 88 VGPRs (R7). Needs the >=128-VGPR budget provided by
// the kernel's waves_per_eu(4,4) pin (default 8-wave target allocates 64 and
// spills the sort to scratch -- R5 measured).
__device__ __forceinline__ float pair_area(const float* __restrict__ A,
                                           const float* __restrict__ B)
{
    float ax = A[0], ay = A[1], adx = A[3], ady = A[4], ayaw = A[6];
    float bx = B[0], by = B[1], bdx = B[3], bdy = B[4], byaw = B[6];

    float ca = __builtin_cosf(ayaw), sa = __builtin_sinf(ayaw);
    float cb = __builtin_cosf(byaw), sb = __builtin_sinf(byaw);

    const float tx[4] = {0.5f, 0.5f, -0.5f, -0.5f};
    const float ty[4] = {0.5f, -0.5f, -0.5f, 0.5f};

    float cax[4], cay[4], cbx[4], cby[4];
#pragma unroll
    for (int k = 0; k < 4; ++k) {
        float lx = tx[k] * adx, ly = ty[k] * ady;
        cax[k] = lx * ca - ly * sa + ax;
        cay[k] = lx * sa + ly * ca + ay;
        lx = tx[k] * bdx; ly = ty[k] * bdy;
        cbx[k] = lx * cb - ly * sb + bx;
        cby[k] = lx * sb + ly * cb + by;
    }

    float px[NPTS], py[NPTS];
    bool valid[NPTS];

#pragma unroll
    for (int k = 0; k < 4; ++k) {
        float relx = cax[k] - bx, rely = cay[k] - by;
        float rx = relx * cb + rely * sb;
        float ry = -relx * sb + rely * cb;
        valid[k] = (fabsf(rx) <= bdx * 0.5f + 1e-5f) &&
                   (fabsf(ry) <= bdy * 0.5f + 1e-5f);
        px[k] = cax[k]; py[k] = cay[k];
    }
#pragma unroll
    for (int k = 0; k < 4; ++k) {
        float relx = cbx[k] - ax, rely = cby[k] - ay;
        float rx = relx * ca + rely * sa;
        float ry = -relx * sa + rely * ca;
        valid[4 + k] = (fabsf(rx) <= adx * 0.5f + 1e-5f) &&
                       (fabsf(ry) <= ady * 0.5f + 1e-5f);
        px[4 + k] = cbx[k]; py[4 + k] = cby[k];
    }

#pragma unroll
    for (int a = 0; a < 4; ++a) {
        int a2 = (a + 1) & 3;
        float p1x = cax[a], p1y = cay[a];
        float d1x = cax[a2] - p1x, d1y = cay[a2] - p1y;
#pragma unroll
        for (int b = 0; b < 4; ++b) {
            int b2 = (b + 1) & 3;
            float q1x = cbx[b], q1y = cby[b];
            float d2x = cbx[b2] - q1x, d2y = cby[b2] - q1y;
            float denom = d1x * d2y - d1y * d2x;
            bool dok = fabsf(denom) > EPS;
            float safe = dok ? denom : 1.0f;
            float inv = __builtin_amdgcn_rcpf(safe);
            float dqx = q1x - p1x, dqy = q1y - p1y;
            float t = (dqx * d2y - dqy * d2x) * inv;
            float u = (dqx * d1y - dqy * d1x) * inv;
            bool v = dok && (t >= 0.0f) && (t <= 1.0f) && (u >= 0.0f) && (u <= 1.0f);
            int o = 8 + a * 4 + b;
            px[o] = p1x + t * d1x;
            py[o] = p1y + t * d1y;
            valid[o] = v;
        }
    }

    int cnt = 0;
    float sx = 0.0f, sy = 0.0f;
#pragma unroll
    for (int k = 0; k < NPTS; ++k) {
        if (valid[k]) cnt++;
        float w = valid[k] ? 1.0f : 0.0f;
        sx += px[k] * w;
        sy += py[k] * w;
    }
    float cntf = (float)(cnt > 1 ? cnt : 1);
    float cx_ = sx / cntf, cy_ = sy / cntf;

    unsigned key[NPTS];
#pragma unroll
    for (int k = 0; k < NPTS; ++k) {
        float rx = px[k] - cx_, ry = py[k] - cy_;
        float axx = fabsf(rx), ayy = fabsf(ry);
        float d = fmaxf(axx + ayy, 1e-30f);
        float r = ry * __builtin_amdgcn_rcpf(d);
        float t = (rx >= 0.0f) ? r : ((ry >= 0.0f) ? 2.0f - r : -2.0f - r);
        unsigned u = __float_as_uint(t);
        unsigned ordered = u ^ ((unsigned)((int)u >> 31) | 0x80000000u);
        key[k] = valid[k] ? ((ordered & 0xFFFFFFE0u) | (unsigned)k)
                          : (0xFFFFFF00u | (unsigned)k);
    }

#pragma unroll
    for (int c = 0; c < NET.n; ++c) {
        int lo = NET.lo[c], hi = NET.hi[c];
        bool sw = key[hi] < key[lo];
        unsigned kl = key[lo], kh = key[hi];
        float xl = px[lo], xh = px[hi];
        float yl = py[lo], yh = py[hi];
        key[lo] = sw ? kh : kl;  key[hi] = sw ? kl : kh;
        px[lo]  = sw ? xh : xl;  px[hi]  = sw ? xl : xh;
        py[lo]  = sw ? yh : yl;  py[hi]  = sw ? yl : yh;
    }

    float lastx = 0.0f, lasty = 0.0f;
#pragma unroll
    for (int r = 0; r < NPTS; ++r) {
        bool isLast = (r == cnt - 1);
        lastx = isLast ? px[r] : lastx;
        lasty = isLast ? py[r] : lasty;
    }

    float s = 0.0f;
#pragma unroll
    for (int r = 0; r + 1 < NPTS; ++r) {
        float cr = px[r] * py[r + 1] - px[r + 1] * py[r];
        s += (r + 1 < cnt) ? cr : 0.0f;
    }
    s += (cnt >= 1) ? (lastx * py[0] - px[0] * lasty) : 0.0f;

    float area = 0.5f * fabsf(s);
    return (cnt >= 3) ? area : 0.0f;
}

// ============================================================================
// Row-quad kernel R11 — continue the R10 lever (proven: 19.4->17.0 at
// ROWS 1->2): amortize per-block fixed work across ROWS=4 rows.
//   - grid 250 x 512 threads; 1 block/CU (all-resident, single generation)
//   - 56KB j-section staged once per 4 rows: device staged bytes 28->14MB,
//     per-CU stage latency paid once (was twice)
//   - survivors packed (rl<<12|j): ~48/block -> ONE pair_area round at ~75%
//     lane utilization; device rounds 500->250
//   - LDS 28KB chunk + 16KB worklist = 44.8KB
//   - waves_per_eu(4,4) kept ONLY for its 128-VGPR budget (88 needed, R7
//     measured); actual occupancy is grid-limited and that's fine.
// ============================================================================
__global__ __launch_bounds__(512)
__attribute__((amdgpu_waves_per_eu(4, 4)))
void rowquad_kernel(
    const float* __restrict__ boxes, float* __restrict__ out, int m, int n)
{
    __shared__ __align__(16) float chunk[CHUNKB * 7];      // 28KB raw boxes
    __shared__ unsigned short wl[ROWS * MAXN_LDS];         // packed (rl<<12|j)
    __shared__ unsigned lcnt;

    const int i0   = blockIdx.x * ROWS;
    const int tid  = threadIdx.x;
    const int wv   = tid >> 6;            // 0..7
    const int lane = tid & 63;

    if (tid == 0) lcnt = 0;

    // ---- i-boxes for all rows (broadcast loads) ----
    float xi[ROWS], yi[ROWS], ri[ROWS];
    bool rowok[ROWS];
#pragma unroll
    for (int rl = 0; rl < ROWS; ++rl) {
        int i = i0 + rl;
        rowok[rl] = (i < m);
        int ic = rowok[rl] ? i : (m - 1);
        const float* b = boxes + (size_t)ic * 7;
        float dx = b[3], dy = b[4];
        xi[rl] = b[0]; yi[rl] = b[1];
        ri[rl] = 0.5f * sqrtf(dx * dx + dy * dy) + 0.005f;
    }

    const unsigned long long below = (1ull << lane) - 1ull;

    // ---- chunked stage + multi-row cull ----
    for (int c0 = 0; c0 < n; c0 += CHUNKB) {
        int cb = n - c0; if (cb > CHUNKB) cb = CHUNKB;
        int words = cb * 7;
        const float* src = boxes + (size_t)(m + c0) * 7;

        if ((((size_t)src) & 15) == 0) {
            int n4 = words >> 2;
            const float4* s4 = (const float4*)src;
            float4* d4 = (float4*)chunk;
            for (int t = tid; t < n4; t += 512) d4[t] = s4[t];
            for (int t = (n4 << 2) + tid; t < words; t += 512)
                chunk[t] = src[t];
        } else {
            for (int t = tid; t < words; t += 512) chunk[t] = src[t];
        }
        __syncthreads();   // chunk ready (1st iter also publishes lcnt=0)

        // cull: one box per thread-iter, tested against ALL rows
        for (int tt = tid; tt < cb; tt += 512) {
            int j = c0 + tt;
            const float* bj = &chunk[tt * 7];      // stride-7: 2-way, free
            float xj = bj[0], yj = bj[1];
            float dxj = bj[3], dyj = bj[4];
            float rj = 0.5f * sqrtf(dxj * dxj + dyj * dyj) + 0.005f;

#pragma unroll
            for (int rl = 0; rl < ROWS; ++rl) {
                bool keep = false;
                if (rowok[rl]) {
                    float ddx = xi[rl] - xj, ddy = yi[rl] - yj;
                    float rr = ri[rl] + rj;
                    keep = (ddx * ddx + ddy * ddy) <= rr * rr;
                    if (!keep) out[(size_t)(i0 + rl) * n + j] = 0.0f;
                }
                unsigned long long mask = __ballot(keep);
                int c = __popcll(mask);
                if (c > 0) {
                    int lead = __ffsll(mask) - 1;
                    unsigned base = 0;
                    if (lane == lead) base = atomicAdd(&lcnt, (unsigned)c);
                    base = (unsigned)__shfl((int)base, lead, 64);
                    if (keep) {
                        int rank = __popcll(mask & below);
                        wl[base + rank] =
                            (unsigned short)(((unsigned)rl << 12) | (unsigned)j);
                    }
                }
            }
        }
        __syncthreads();   // chunk consumed; safe to overwrite next iter
    }

    // ---- phase 2: packed survivors; round r handled by wave (bid + r)&7 ----
    unsigned cnt = lcnt;
    unsigned r = 0;
    for (unsigned base = 0; base < cnt; base += 64, ++r) {
        if ((int)(((unsigned)blockIdx.x + r) & 7u) == wv) {
            unsigned t = base + (unsigned)lane;
            if (t < cnt) {
                unsigned e = wl[t];
                int rl = (int)(e >> 12);
                int j  = (int)(e & 0xFFFu);
                int i  = i0 + rl;
                out[(size_t)i * n + j] =
                    pair_area(boxes + (size_t)i * 7,
                              boxes + (size_t)(m + j) * 7);
            }
        }
    }
}

// ============================================================================
// Fallback pipeline — unchanged (only for odd shapes).
// ============================================================================
__global__ __launch_bounds__(256) void prep_kernel(
    const float* __restrict__ boxes, float* __restrict__ xs,
    float* __restrict__ ys, float* __restrict__ rs,
    unsigned* __restrict__ counters, int total)
{
    int t = blockIdx.x * blockDim.x + threadIdx.x;
    if (t < NREG * CTR_STRIDE) counters[t] = 0;
    if (t < total) {
        float dx = boxes[(size_t)t * 7 + 3];
        float dy = boxes[(size_t)t * 7 + 4];
        xs[t] = boxes[(size_t)t * 7 + 0];
        ys[t] = boxes[(size_t)t * 7 + 1];
        rs[t] = 0.5f * sqrtf(dx * dx + dy * dy) + 0.005f;
    }
}

__global__ __launch_bounds__(256) void cull_kernel(
    const float* __restrict__ xs, const float* __restrict__ ys,
    const float* __restrict__ rs, float* __restrict__ out,
    unsigned* __restrict__ counters, unsigned* __restrict__ regions,
    int m, int n, unsigned reg_cap)
{
    int jb = blockIdx.x, i = blockIdx.y;
    int tid = threadIdx.x;
    int j = jb * 256 + tid;

    bool keep = false;
    if (j < n) {
        float dx = xs[i] - xs[m + j];
        float dy = ys[i] - ys[m + j];
        float rr = rs[i] + rs[m + j];
        keep = (dx * dx + dy * dy) <= rr * rr;
        out[(size_t)i * n + j] = 0.0f;
    }

    unsigned long long mask = __ballot(keep);
    if (mask == 0ull) return;

    int lane = tid & 63;
    unsigned gwid = ((unsigned)(i * gridDim.x + jb) << 2) | ((unsigned)tid >> 6);
    unsigned region = gwid & (NREG - 1);

    int c = __popcll(mask);
    int lead = __ffsll((unsigned long long)mask) - 1;
    unsigned pos = 0;
    if (lane == lead) pos = atomicAdd(&counters[region * CTR_STRIDE], (unsigned)c);
    pos = (unsigned)__shfl((int)pos, lead, 64);
    if (keep) {
        int rank = __popcll(mask & ((1ull << lane) - 1ull));
        regions[(size_t)region * reg_cap + pos + rank] =
            ((unsigned)i << 12) | (unsigned)j;
    }
}

__global__ __launch_bounds__(64) void process_kernel(
    const float* __restrict__ boxes, float* __restrict__ out,
    const unsigned* __restrict__ counters, const unsigned* __restrict__ regions,
    int m, int n, unsigned reg_cap)
{
    unsigned region = blockIdx.x >> 2;
    unsigned cnt = counters[region * CTR_STRIDE];
    const unsigned* seg = regions + (size_t)region * reg_cap;
    for (unsigned t = ((blockIdx.x & 3u) << 6) | threadIdx.x; t < cnt; t += 256) {
        unsigned v = seg[t];
        int i = (int)(v >> 12);
        int j = (int)(v & 4095u);
        const float* A = boxes + (size_t)i * 7;
        const float* B = boxes + (size_t)(m + j) * 7;
        out[(size_t)i * n + j] = pair_area(A, B);
    }
}

__global__ __launch_bounds__(256) void overlap_kernel(
    const float* __restrict__ boxes, float* __restrict__ out, int m, int n)
{
    int j = blockIdx.x * blockDim.x + threadIdx.x;
    int i = blockIdx.y;
    if (j >= n) return;
    const float* A = boxes + (size_t)i * 7;
    const float* B = boxes + (size_t)(m + j) * 7;
    out[(size_t)i * n + j] = pair_area(A, B);
}

extern "C" void kernel_launch(void* const* d_in, const int* in_sizes, int n_in,
                              void* d_out, int out_size, void* d_ws, size_t ws_size,
                              hipStream_t stream) {
    const float* boxes = (const float*)d_in[0];
    float* out = (float*)d_out;
    int total = in_sizes[0] / 7;   // 3000 boxes
    int m = total / 3;             // 1000
    int n = total - m;             // 2000

    // ---------------- single-dispatch row-quad kernel ----------------
    if (n > 0 && n <= MAXN_LDS && m >= 1) {
        int nb = (m + ROWS - 1) / ROWS;
        hipLaunchKernelGGL(rowquad_kernel, dim3((unsigned)nb), dim3(512),
                           0, stream, boxes, out, m, n);
        return;
    }

    // ---------------- fallback: verified 3-kernel pipeline ----------------
    int bpr = (n + 255) / 256;
    unsigned total_waves = (unsigned)(bpr * m) * 4u;
    unsigned reg_cap = ((total_waves + NREG - 1) / NREG) * 64u;

    size_t ctr_off = 0;
    size_t xs_off  = ctr_off + (size_t)NREG * CTR_STRIDE * 4;
    size_t ys_off  = xs_off + (size_t)total * 4;
    size_t rs_off  = ys_off + (size_t)total * 4;
    size_t reg_off = ((rs_off + (size_t)total * 4) + 255) & ~(size_t)255;
    size_t need    = reg_off + (size_t)NREG * reg_cap * 4;

    if (ws_size < need || n > 4095) {
        dim3 block(256, 1, 1);
        dim3 grid((n + 255) / 256, m, 1);
        hipLaunchKernelGGL(overlap_kernel, grid, block, 0, stream, boxes, out, m, n);
        return;
    }

    unsigned* counters = (unsigned*)((char*)d_ws + ctr_off);
    float* xs = (float*)((char*)d_ws + xs_off);
    float* ys = (float*)((char*)d_ws + ys_off);
    float* rs = (float*)((char*)d_ws + rs_off);
    unsigned* regions = (unsigned*)((char*)d_ws + reg_off);

    int prep_threads = (NREG * CTR_STRIDE > total) ? NREG * CTR_STRIDE : total;
    hipLaunchKernelGGL(prep_kernel, dim3((prep_threads + 255) / 256), dim3(256),
                       0, stream, boxes, xs, ys, rs, counters, total);

    hipLaunchKernelGGL(cull_kernel, dim3(bpr, m, 1), dim3(256), 0, stream,
                       xs, ys, rs, out, counters, regions, m, n, reg_cap);

    hipLaunchKernelGGL(process_kernel, dim3(NREG * 4, 1, 1), dim3(64), 0, stream,
                       boxes, out, counters, regions, m, n, reg_cap);
}

// Round 12
// 15.898 us; speedup vs baseline: 1.1184x; 1.1184x over previous
//
#include <hip/hip_runtime.h>
#include <math.h>
#include <utility>

#define EPS 1e-8f
#define NPTS 24
#define MAXN_LDS 2048      // row kernel supports n <= 2048
#define CHUNKB 1024        // boxes staged per chunk (28KB raw)
#define ROWS 2             // rows per block (R10 sweet spot)
#define NREG 64            // fallback pipeline worklist regions
#define CTR_STRIDE 64

// ---- constexpr Batcher odd-even mergesort comparator network for NPTS=24 ----
struct Net {
    int n;
    unsigned char lo[256];
    unsigned char hi[256];
};
constexpr Net build_net() {
    Net net{};
    net.n = 0;
    for (int p = 1; p < NPTS; p <<= 1)
        for (int k = p; k >= 1; k >>= 1)
            for (int j = k % p; j + k < NPTS; j += 2 * k)
                for (int i = 0; i < k && i + j + k < NPTS; ++i)
                    if ((i + j) / (2 * p) == (i + j + k) / (2 * p)) {
                        net.lo[net.n] = (unsigned char)(i + j);
                        net.hi[net.n] = (unsigned char)(i + j + k);
                        ++net.n;
                    }
    return net;
}
constexpr Net NET = build_net();

// ---- template-forced constant-index key-only sort network (verified R4) ----
template <int C>
__device__ __forceinline__ void sort_step(unsigned (&key)[NPTS]) {
    constexpr int lo = NET.lo[C];
    constexpr int hi = NET.hi[C];
    unsigned a = key[lo], b = key[hi];
    key[lo] = (a < b) ? a : b;   // v_min_u32
    key[hi] = (a < b) ? b : a;   // v_max_u32
}
template <int... Cs>
__device__ __forceinline__ void sort_net_impl(unsigned (&key)[NPTS],
                                              std::integer_sequence<int, Cs...>) {
    (sort_step<Cs>(key), ...);   // comma-fold: strict left-to-right order
}
__device__ __forceinline__ void sort_net(unsigned (&key)[NPTS]) {
    sort_net_impl(key, std::make_integer_sequence<int, NET.n>{});
}

// ============================================================================
// Phase-2 heavy path (VERIFIED in R4, absmax 0.03125): key-only register sort
// (2 instrs/comparator vs 7 for the sort-everything version -> ~400 fewer
// instrs on the tail-critical wave) + per-lane LDS point columns:
//   x at scr[k*64+lane], y at scr[NPTS*64 + k*64+lane]; bank = lane%32 ->
//   2 lanes/bank = free. Footprint 2*24*64 floats = 12KB per calling wave.
// FP ops/order identical to the verified register pair_area (bit-identical).
// ============================================================================
__device__ __forceinline__ float pair_area_lds(const float* __restrict__ A,
                                               const float* __restrict__ B,
                                               float* __restrict__ scr, int lane)
{
    float ax = A[0], ay = A[1], adx = A[3], ady = A[4], ayaw = A[6];
    float bx = B[0], by = B[1], bdx = B[3], bdy = B[4], byaw = B[6];

    float ca = __builtin_cosf(ayaw), sa = __builtin_sinf(ayaw);
    float cb = __builtin_cosf(byaw), sb = __builtin_sinf(byaw);

    const float tx[4] = {0.5f, 0.5f, -0.5f, -0.5f};
    const float ty[4] = {0.5f, -0.5f, -0.5f, 0.5f};

    float cax[4], cay[4], cbx[4], cby[4];
#pragma unroll
    for (int k = 0; k < 4; ++k) {
        float lx = tx[k] * adx, ly = ty[k] * ady;
        cax[k] = lx * ca - ly * sa + ax;
        cay[k] = lx * sa + ly * ca + ay;
        lx = tx[k] * bdx; ly = ty[k] * bdy;
        cbx[k] = lx * cb - ly * sb + bx;
        cby[k] = lx * sb + ly * cb + by;
    }

    float* sxc = scr;                   // x columns
    float* syc = scr + NPTS * 64;       // y columns

    unsigned vm = 0;
    float accx = 0.0f, accy = 0.0f;

    // A corners vs B (slots 0..3)
#pragma unroll
    for (int k = 0; k < 4; ++k) {
        float relx = cax[k] - bx, rely = cay[k] - by;
        float rx = relx * cb + rely * sb;
        float ry = -relx * sb + rely * cb;
        bool v = (fabsf(rx) <= bdx * 0.5f + 1e-5f) &&
                 (fabsf(ry) <= bdy * 0.5f + 1e-5f);
        vm |= (v ? 1u : 0u) << k;
        float w = v ? 1.0f : 0.0f;
        accx += cax[k] * w; accy += cay[k] * w;
        sxc[k * 64 + lane] = cax[k];
        syc[k * 64 + lane] = cay[k];
    }
    // B corners vs A (slots 4..7)
#pragma unroll
    for (int k = 0; k < 4; ++k) {
        float relx = cbx[k] - ax, rely = cby[k] - ay;
        float rx = relx * ca + rely * sa;
        float ry = -relx * sa + rely * ca;
        bool v = (fabsf(rx) <= adx * 0.5f + 1e-5f) &&
                 (fabsf(ry) <= ady * 0.5f + 1e-5f);
        vm |= (v ? 1u : 0u) << (4 + k);
        float w = v ? 1.0f : 0.0f;
        accx += cbx[k] * w; accy += cby[k] * w;
        sxc[(4 + k) * 64 + lane] = cbx[k];
        syc[(4 + k) * 64 + lane] = cby[k];
    }
    // edge intersections (slots 8..23)
#pragma unroll
    for (int a = 0; a < 4; ++a) {
        int a2 = (a + 1) & 3;
        float p1x = cax[a], p1y = cay[a];
        float d1x = cax[a2] - p1x, d1y = cay[a2] - p1y;
#pragma unroll
        for (int b = 0; b < 4; ++b) {
            int b2 = (b + 1) & 3;
            float q1x = cbx[b], q1y = cby[b];
            float d2x = cbx[b2] - q1x, d2y = cby[b2] - q1y;
            float denom = d1x * d2y - d1y * d2x;
            bool dok = fabsf(denom) > EPS;
            float safe = dok ? denom : 1.0f;
            float inv = __builtin_amdgcn_rcpf(safe);
            float dqx = q1x - p1x, dqy = q1y - p1y;
            float t = (dqx * d2y - dqy * d2x) * inv;
            float u = (dqx * d1y - dqy * d1x) * inv;
            bool v = dok && (t >= 0.0f) && (t <= 1.0f) && (u >= 0.0f) && (u <= 1.0f);
            int o = 8 + a * 4 + b;
            float ipx = p1x + t * d1x;
            float ipy = p1y + t * d1y;
            vm |= (v ? 1u : 0u) << o;
            float w = v ? 1.0f : 0.0f;
            accx += ipx * w; accy += ipy * w;
            sxc[o * 64 + lane] = ipx;
            syc[o * 64 + lane] = ipy;
        }
    }

    int cnt = __popc(vm);
    float cntf = (float)(cnt > 1 ? cnt : 1);
    float cx_ = accx / cntf, cy_ = accy / cntf;

    unsigned key[NPTS];
#pragma unroll
    for (int k = 0; k < NPTS; ++k) {
        float x = sxc[k * 64 + lane];
        float y = syc[k * 64 + lane];
        float rx = x - cx_, ry = y - cy_;
        float axx = fabsf(rx), ayy = fabsf(ry);
        float d = fmaxf(axx + ayy, 1e-30f);
        float r = ry * __builtin_amdgcn_rcpf(d);
        float t = (rx >= 0.0f) ? r : ((ry >= 0.0f) ? 2.0f - r : -2.0f - r);
        unsigned u = __float_as_uint(t);
        unsigned ordered = u ^ ((unsigned)((int)u >> 31) | 0x80000000u);
        bool v = (vm >> k) & 1u;
        key[k] = v ? ((ordered & 0xFFFFFFE0u) | (unsigned)k)
                   : (0xFFFFFF00u | (unsigned)k);
    }

    sort_net(key);

    // sorted walk: gather each lane's own columns by embedded slot index
    float s = 0.0f, x0 = 0.0f, y0 = 0.0f;
    float prevx = 0.0f, prevy = 0.0f, lastx = 0.0f, lasty = 0.0f;
#pragma unroll
    for (int r = 0; r < NPTS; ++r) {
        int j = (int)(key[r] & 31u);               // slot < 24 by construction
        float xr = sxc[j * 64 + lane];
        float yr = syc[j * 64 + lane];
        if (r == 0) { x0 = xr; y0 = yr; }
        else s += (r < cnt) ? (prevx * yr - xr * prevy) : 0.0f;
        bool isLast = (r == cnt - 1);
        lastx = isLast ? xr : lastx;
        lasty = isLast ? yr : lasty;
        prevx = xr; prevy = yr;
    }
    s += (cnt >= 1) ? (lastx * y0 - x0 * lasty) : 0.0f;

    float area = 0.5f * fabsf(s);
    return (cnt >= 3) ? area : 0.0f;
}

// ---- register-array heavy path (fallback kernels only) ----
__device__ __forceinline__ float pair_area(const float* __restrict__ A,
                                           const float* __restrict__ B)
{
    float ax = A[0], ay = A[1], adx = A[3], ady = A[4], ayaw = A[6];
    float bx = B[0], by = B[1], bdx = B[3], bdy = B[4], byaw = B[6];

    float ca = __builtin_cosf(ayaw), sa = __builtin_sinf(ayaw);
    float cb = __builtin_cosf(byaw), sb = __builtin_sinf(byaw);

    const float tx[4] = {0.5f, 0.5f, -0.5f, -0.5f};
    const float ty[4] = {0.5f, -0.5f, -0.5f, 0.5f};

    float cax[4], cay[4], cbx[4], cby[4];
#pragma unroll
    for (int k = 0; k < 4; ++k) {
        float lx = tx[k] * adx, ly = ty[k] * ady;
        cax[k] = lx * ca - ly * sa + ax;
        cay[k] = lx * sa + ly * ca + ay;
        lx = tx[k] * bdx; ly = ty[k] * bdy;
        cbx[k] = lx * cb - ly * sb + bx;
        cby[k] = lx * sb + ly * cb + by;
    }

    float px[NPTS], py[NPTS];
    bool valid[NPTS];

#pragma unroll
    for (int k = 0; k < 4; ++k) {
        float relx = cax[k] - bx, rely = cay[k] - by;
        float rx = relx * cb + rely * sb;
        float ry = -relx * sb + rely * cb;
        valid[k] = (fabsf(rx) <= bdx * 0.5f + 1e-5f) &&
                   (fabsf(ry) <= bdy * 0.5f + 1e-5f);
        px[k] = cax[k]; py[k] = cay[k];
    }
#pragma unroll
    for (int k = 0; k < 4; ++k) {
        float relx = cbx[k] - ax, rely = cby[k] - ay;
        float rx = relx * ca + rely * sa;
        float ry = -relx * sa + rely * ca;
        valid[4 + k] = (fabsf(rx) <= adx * 0.5f + 1e-5f) &&
                       (fabsf(ry) <= ady * 0.5f + 1e-5f);
        px[4 + k] = cbx[k]; py[4 + k] = cby[k];
    }

#pragma unroll
    for (int a = 0; a < 4; ++a) {
        int a2 = (a + 1) & 3;
        float p1x = cax[a], p1y = cay[a];
        float d1x = cax[a2] - p1x, d1y = cay[a2] - p1y;
#pragma unroll
        for (int b = 0; b < 4; ++b) {
            int b2 = (b + 1) & 3;
            float q1x = cbx[b], q1y = cby[b];
            float d2x = cbx[b2] - q1x, d2y = cby[b2] - q1y;
            float denom = d1x * d2y - d1y * d2x;
            bool dok = fabsf(denom) > EPS;
            float safe = dok ? denom : 1.0f;
            float inv = __builtin_amdgcn_rcpf(safe);
            float dqx = q1x - p1x, dqy = q1y - p1y;
            float t = (dqx * d2y - dqy * d2x) * inv;
            float u = (dqx * d1y - dqy * d1x) * inv;
            bool v = dok && (t >= 0.0f) && (t <= 1.0f) && (u >= 0.0f) && (u <= 1.0f);
            int o = 8 + a * 4 + b;
            px[o] = p1x + t * d1x;
            py[o] = p1y + t * d1y;
            valid[o] = v;
        }
    }

    int cnt = 0;
    float sx = 0.0f, sy = 0.0f;
#pragma unroll
    for (int k = 0; k < NPTS; ++k) {
        if (valid[k]) cnt++;
        float w = valid[k] ? 1.0f : 0.0f;
        sx += px[k] * w;
        sy += py[k] * w;
    }
    float cntf = (float)(cnt > 1 ? cnt : 1);
    float cx_ = sx / cntf, cy_ = sy / cntf;

    unsigned key[NPTS];
#pragma unroll
    for (int k = 0; k < NPTS; ++k) {
        float rx = px[k] - cx_, ry = py[k] - cy_;
        float axx = fabsf(rx), ayy = fabsf(ry);
        float d = fmaxf(axx + ayy, 1e-30f);
        float r = ry * __builtin_amdgcn_rcpf(d);
        float t = (rx >= 0.0f) ? r : ((ry >= 0.0f) ? 2.0f - r : -2.0f - r);
        unsigned u = __float_as_uint(t);
        unsigned ordered = u ^ ((unsigned)((int)u >> 31) | 0x80000000u);
        key[k] = valid[k] ? ((ordered & 0xFFFFFFE0u) | (unsigned)k)
                          : (0xFFFFFF00u | (unsigned)k);
    }

#pragma unroll
    for (int c = 0; c < NET.n; ++c) {
        int lo = NET.lo[c], hi = NET.hi[c];
        bool sw = key[hi] < key[lo];
        unsigned kl = key[lo], kh = key[hi];
        float xl = px[lo], xh = px[hi];
        float yl = py[lo], yh = py[hi];
        key[lo] = sw ? kh : kl;  key[hi] = sw ? kl : kh;
        px[lo]  = sw ? xh : xl;  px[hi]  = sw ? xl : xh;
        py[lo]  = sw ? yh : yl;  py[hi]  = sw ? yl : yh;
    }

    float lastx = 0.0f, lasty = 0.0f;
#pragma unroll
    for (int r = 0; r < NPTS; ++r) {
        bool isLast = (r == cnt - 1);
        lastx = isLast ? px[r] : lastx;
        lasty = isLast ? py[r] : lasty;
    }

    float s = 0.0f;
#pragma unroll
    for (int r = 0; r + 1 < NPTS; ++r) {
        float cr = px[r] * py[r + 1] - px[r + 1] * py[r];
        s += (r + 1 < cnt) ? cr : 0.0f;
    }
    s += (cnt >= 1) ? (lastx * py[0] - px[0] * lasty) : 0.0f;

    float area = 0.5f * fabsf(s);
    return (cnt >= 3) ? area : 0.0f;
}

// ============================================================================
// Row-pair kernel R12 — R10 shell (proven 17.0us; R11's ROWS=4 regressed via
// grid 250 < 256 CUs) + phase-2 heavy path swapped to the R4-verified
// pair_area_lds (key-only sort: ~400 fewer instrs on the tail wave).
//   - scr = chunk (28KB, dead after final cull barrier; need 12KB)
//   - ALL rounds on one fixed owner wave (bid&7): no scratch collision even
//     for adversarial survivor counts (rounds serialize on that wave)
//   - occupancy identical to R10: LDS 36.6KB, waves_per_eu(4,4) -> 128-VGPR
//     budget, 2 blocks x 8 waves = 16 waves/CU
// ============================================================================
__global__ __launch_bounds__(512)
__attribute__((amdgpu_waves_per_eu(4, 4)))
void rowpair_kernel(
    const float* __restrict__ boxes, float* __restrict__ out, int m, int n)
{
    __shared__ __align__(16) float chunk[CHUNKB * 7];      // 28KB raw boxes
    __shared__ unsigned short wl[ROWS * MAXN_LDS];         // packed (rl<<12|j)
    __shared__ unsigned lcnt;

    const int i0   = blockIdx.x * ROWS;
    const int tid  = threadIdx.x;
    const int wv   = tid >> 6;            // 0..7
    const int lane = tid & 63;

    if (tid == 0) lcnt = 0;

    // ---- i-boxes for both rows (broadcast loads) ----
    float xi[ROWS], yi[ROWS], ri[ROWS];
    bool rowok[ROWS];
#pragma unroll
    for (int rl = 0; rl < ROWS; ++rl) {
        int i = i0 + rl;
        rowok[rl] = (i < m);
        int ic = rowok[rl] ? i : (m - 1);
        const float* b = boxes + (size_t)ic * 7;
        float dx = b[3], dy = b[4];
        xi[rl] = b[0]; yi[rl] = b[1];
        ri[rl] = 0.5f * sqrtf(dx * dx + dy * dy) + 0.005f;
    }

    const unsigned long long below = (1ull << lane) - 1ull;

    // ---- chunked stage + dual-row cull (R10, unchanged) ----
    for (int c0 = 0; c0 < n; c0 += CHUNKB) {
        int cb = n - c0; if (cb > CHUNKB) cb = CHUNKB;
        int words = cb * 7;
        const float* src = boxes + (size_t)(m + c0) * 7;

        if ((((size_t)src) & 15) == 0) {
            int n4 = words >> 2;
            const float4* s4 = (const float4*)src;
            float4* d4 = (float4*)chunk;
            for (int t = tid; t < n4; t += 512) d4[t] = s4[t];
            for (int t = (n4 << 2) + tid; t < words; t += 512)
                chunk[t] = src[t];
        } else {
            for (int t = tid; t < words; t += 512) chunk[t] = src[t];
        }
        __syncthreads();   // chunk ready (1st iter also publishes lcnt=0)

        for (int tt = tid; tt < cb; tt += 512) {
            int j = c0 + tt;
            const float* bj = &chunk[tt * 7];      // stride-7: 2-way, free
            float xj = bj[0], yj = bj[1];
            float dxj = bj[3], dyj = bj[4];
            float rj = 0.5f * sqrtf(dxj * dxj + dyj * dyj) + 0.005f;

#pragma unroll
            for (int rl = 0; rl < ROWS; ++rl) {
                bool keep = false;
                if (rowok[rl]) {
                    float ddx = xi[rl] - xj, ddy = yi[rl] - yj;
                    float rr = ri[rl] + rj;
                    keep = (ddx * ddx + ddy * ddy) <= rr * rr;
                    if (!keep) out[(size_t)(i0 + rl) * n + j] = 0.0f;
                }
                unsigned long long mask = __ballot(keep);
                int c = __popcll(mask);
                if (c > 0) {
                    int lead = __ffsll(mask) - 1;
                    unsigned base = 0;
                    if (lane == lead) base = atomicAdd(&lcnt, (unsigned)c);
                    base = (unsigned)__shfl((int)base, lead, 64);
                    if (keep) {
                        int rank = __popcll(mask & below);
                        wl[base + rank] =
                            (unsigned short)(((unsigned)rl << 12) | (unsigned)j);
                    }
                }
            }
        }
        __syncthreads();   // chunk consumed; safe to overwrite next iter
    }

    // ---- phase 2: owner wave processes all survivors; chunk is dead ->
    //      its first 12KB serve as the owner wave's point-column scratch ----
    unsigned cnt = lcnt;
    if (wv == (int)(blockIdx.x & 7u)) {
        float* scr = chunk;                    // 12KB needed, 28KB available
        for (unsigned base = 0; base < cnt; base += 64) {
            unsigned t = base + (unsigned)lane;
            if (t < cnt) {
                unsigned e = wl[t];
                int rl = (int)(e >> 12);
                int j  = (int)(e & 0xFFFu);
                int i  = i0 + rl;
                out[(size_t)i * n + j] =
                    pair_area_lds(boxes + (size_t)i * 7,
                                  boxes + (size_t)(m + j) * 7, scr, lane);
            }
        }
    }
}

// ============================================================================
// Fallback pipeline — unchanged (only for odd shapes).
// ============================================================================
__global__ __launch_bounds__(256) void prep_kernel(
    const float* __restrict__ boxes, float* __restrict__ xs,
    float* __restrict__ ys, float* __restrict__ rs,
    unsigned* __restrict__ counters, int total)
{
    int t = blockIdx.x * blockDim.x + threadIdx.x;
    if (t < NREG * CTR_STRIDE) counters[t] = 0;
    if (t < total) {
        float dx = boxes[(size_t)t * 7 + 3];
        float dy = boxes[(size_t)t * 7 + 4];
        xs[t] = boxes[(size_t)t * 7 + 0];
        ys[t] = boxes[(size_t)t * 7 + 1];
        rs[t] = 0.5f * sqrtf(dx * dx + dy * dy) + 0.005f;
    }
}

__global__ __launch_bounds__(256) void cull_kernel(
    const float* __restrict__ xs, const float* __restrict__ ys,
    const float* __restrict__ rs, float* __restrict__ out,
    unsigned* __restrict__ counters, unsigned* __restrict__ regions,
    int m, int n, unsigned reg_cap)
{
    int jb = blockIdx.x, i = blockIdx.y;
    int tid = threadIdx.x;
    int j = jb * 256 + tid;

    bool keep = false;
    if (j < n) {
        float dx = xs[i] - xs[m + j];
        float dy = ys[i] - ys[m + j];
        float rr = rs[i] + rs[m + j];
        keep = (dx * dx + dy * dy) <= rr * rr;
        out[(size_t)i * n + j] = 0.0f;
    }

    unsigned long long mask = __ballot(keep);
    if (mask == 0ull) return;

    int lane = tid & 63;
    unsigned gwid = ((unsigned)(i * gridDim.x + jb) << 2) | ((unsigned)tid >> 6);
    unsigned region = gwid & (NREG - 1);

    int c = __popcll(mask);
    int lead = __ffsll((unsigned long long)mask) - 1;
    unsigned pos = 0;
    if (lane == lead) pos = atomicAdd(&counters[region * CTR_STRIDE], (unsigned)c);
    pos = (unsigned)__shfl((int)pos, lead, 64);
    if (keep) {
        int rank = __popcll(mask & ((1ull << lane) - 1ull));
        regions[(size_t)region * reg_cap + pos + rank] =
            ((unsigned)i << 12) | (unsigned)j;
    }
}

__global__ __launch_bounds__(64) void process_kernel(
    const float* __restrict__ boxes, float* __restrict__ out,
    const unsigned* __restrict__ counters, const unsigned* __restrict__ regions,
    int m, int n, unsigned reg_cap)
{
    unsigned region = blockIdx.x >> 2;
    unsigned cnt = counters[region * CTR_STRIDE];
    const unsigned* seg = regions + (size_t)region * reg_cap;
    for (unsigned t = ((blockIdx.x & 3u) << 6) | threadIdx.x; t < cnt; t += 256) {
        unsigned v = seg[t];
        int i = (int)(v >> 12);
        int j = (int)(v & 4095u);
        const float* A = boxes + (size_t)i * 7;
        const float* B = boxes + (size_t)(m + j) * 7;
        out[(size_t)i * n + j] = pair_area(A, B);
    }
}

__global__ __launch_bounds__(256) void overlap_kernel(
    const float* __restrict__ boxes, float* __restrict__ out, int m, int n)
{
    int j = blockIdx.x * blockDim.x + threadIdx.x;
    int i = blockIdx.y;
    if (j >= n) return;
    const float* A = boxes + (size_t)i * 7;
    const float* B = boxes + (size_t)(m + j) * 7;
    out[(size_t)i * n + j] = pair_area(A, B);
}

extern "C" void kernel_launch(void* const* d_in, const int* in_sizes, int n_in,
                              void* d_out, int out_size, void* d_ws, size_t ws_size,
                              hipStream_t stream) {
    const float* boxes = (const float*)d_in[0];
    float* out = (float*)d_out;
    int total = in_sizes[0] / 7;   // 3000 boxes
    int m = total / 3;             // 1000
    int n = total - m;             // 2000

    // ---------------- single-dispatch row-pair kernel ----------------
    if (n > 0 && n <= MAXN_LDS && m >= 1) {
        int nb = (m + ROWS - 1) / ROWS;
        hipLaunchKernelGGL(rowpair_kernel, dim3((unsigned)nb), dim3(512),
                           0, stream, boxes, out, m, n);
        return;
    }

    // ---------------- fallback: verified 3-kernel pipeline ----------------
    int bpr = (n + 255) / 256;
    unsigned total_waves = (unsigned)(bpr * m) * 4u;
    unsigned reg_cap = ((total_waves + NREG - 1) / NREG) * 64u;

    size_t ctr_off = 0;
    size_t xs_off  = ctr_off + (size_t)NREG * CTR_STRIDE * 4;
    size_t ys_off  = xs_off + (size_t)total * 4;
    size_t rs_off  = ys_off + (size_t)total * 4;
    size_t reg_off = ((rs_off + (size_t)total * 4) + 255) & ~(size_t)255;
    size_t need    = reg_off + (size_t)NREG * reg_cap * 4;

    if (ws_size < need || n > 4095) {
        dim3 block(256, 1, 1);
        dim3 grid((n + 255) / 256, m, 1);
        hipLaunchKernelGGL(overlap_kernel, grid, block, 0, stream, boxes, out, m, n);
        return;
    }

    unsigned* counters = (unsigned*)((char*)d_ws + ctr_off);
    float* xs = (float*)((char*)d_ws + xs_off);
    float* ys = (float*)((char*)d_ws + ys_off);
    float* rs = (float*)((char*)d_ws + rs_off);
    unsigned* regions = (unsigned*)((char*)d_ws + reg_off);

    int prep_threads = (NREG * CTR_STRIDE > total) ? NREG * CTR_STRIDE : total;
    hipLaunchKernelGGL(prep_kernel, dim3((prep_threads + 255) / 256), dim3(256),
                       0, stream, boxes, xs, ys, rs, counters, total);

    hipLaunchKernelGGL(cull_kernel, dim3(bpr, m, 1), dim3(256), 0, stream,
                       xs, ys, rs, out, counters, regions, m, n, reg_cap);

    hipLaunchKernelGGL(process_kernel, dim3(NREG * 4, 1, 1), dim3(64), 0, stream,
                       boxes, out, counters, regions, m, n, reg_cap);
}

// Round 13
// 15.866 us; speedup vs baseline: 1.1206x; 1.0020x over previous
//
#include <hip/hip_runtime.h>
#include <math.h>
#include <utility>

#define EPS 1e-8f
#define NPTS 24
#define MAXN_LDS 2048      // row kernel supports n <= 2048
#define CHUNKB 1024        // boxes staged per chunk (28KB raw)
#define ROWS 2             // rows per block (R10 sweet spot)
#define NREG 64            // fallback pipeline worklist regions
#define CTR_STRIDE 64

// ---- constexpr Batcher odd-even mergesort comparator network for NPTS=24 ----
struct Net {
    int n;
    unsigned char lo[256];
    unsigned char hi[256];
};
constexpr Net build_net() {
    Net net{};
    net.n = 0;
    for (int p = 1; p < NPTS; p <<= 1)
        for (int k = p; k >= 1; k >>= 1)
            for (int j = k % p; j + k < NPTS; j += 2 * k)
                for (int i = 0; i < k && i + j + k < NPTS; ++i)
                    if ((i + j) / (2 * p) == (i + j + k) / (2 * p)) {
                        net.lo[net.n] = (unsigned char)(i + j);
                        net.hi[net.n] = (unsigned char)(i + j + k);
                        ++net.n;
                    }
    return net;
}
constexpr Net NET = build_net();

// ---- template-forced constant-index key-only sort network (verified R4) ----
template <int C>
__device__ __forceinline__ void sort_step(unsigned (&key)[NPTS]) {
    constexpr int lo = NET.lo[C];
    constexpr int hi = NET.hi[C];
    unsigned a = key[lo], b = key[hi];
    key[lo] = (a < b) ? a : b;   // v_min_u32
    key[hi] = (a < b) ? b : a;   // v_max_u32
}
template <int... Cs>
__device__ __forceinline__ void sort_net_impl(unsigned (&key)[NPTS],
                                              std::integer_sequence<int, Cs...>) {
    (sort_step<Cs>(key), ...);   // comma-fold: strict left-to-right order
}
__device__ __forceinline__ void sort_net(unsigned (&key)[NPTS]) {
    sort_net_impl(key, std::make_integer_sequence<int, NET.n>{});
}

// ============================================================================
// Phase-2 heavy path R13: R12's pair_area_lds with the key build moved to
// REGISTERS. R12 wrote points to LDS then read all 48 back for the key build
// -- 48 dependent ds_read (~120cyc first-use) on the tail wave's serial
// chain. Here px/py stay live in registers through the key build (peak ~90
// regs, inside the 128 budget; dead before the sort), and LDS columns serve
// ONLY the dynamic-index sorted gather. FP ops/order identical (bit-exact).
//   LDS columns: x at scr[k*64+lane], y at scr[NPTS*64+k*64+lane];
//   bank = lane%32 -> 2 lanes/bank = free.
// ============================================================================
__device__ __forceinline__ float pair_area_lds(const float* __restrict__ A,
                                               const float* __restrict__ B,
                                               float* __restrict__ scr, int lane)
{
    float ax = A[0], ay = A[1], adx = A[3], ady = A[4], ayaw = A[6];
    float bx = B[0], by = B[1], bdx = B[3], bdy = B[4], byaw = B[6];

    float ca = __builtin_cosf(ayaw), sa = __builtin_sinf(ayaw);
    float cb = __builtin_cosf(byaw), sb = __builtin_sinf(byaw);

    const float tx[4] = {0.5f, 0.5f, -0.5f, -0.5f};
    const float ty[4] = {0.5f, -0.5f, -0.5f, 0.5f};

    float cax[4], cay[4], cbx[4], cby[4];
#pragma unroll
    for (int k = 0; k < 4; ++k) {
        float lx = tx[k] * adx, ly = ty[k] * ady;
        cax[k] = lx * ca - ly * sa + ax;
        cay[k] = lx * sa + ly * ca + ay;
        lx = tx[k] * bdx; ly = ty[k] * bdy;
        cbx[k] = lx * cb - ly * sb + bx;
        cby[k] = lx * sb + ly * cb + by;
    }

    float* sxc = scr;                   // x columns (gather only)
    float* syc = scr + NPTS * 64;       // y columns (gather only)

    float px[NPTS], py[NPTS];           // register copies for the key build
    unsigned vm = 0;
    float accx = 0.0f, accy = 0.0f;

    // A corners vs B (slots 0..3)
#pragma unroll
    for (int k = 0; k < 4; ++k) {
        float relx = cax[k] - bx, rely = cay[k] - by;
        float rx = relx * cb + rely * sb;
        float ry = -relx * sb + rely * cb;
        bool v = (fabsf(rx) <= bdx * 0.5f + 1e-5f) &&
                 (fabsf(ry) <= bdy * 0.5f + 1e-5f);
        vm |= (v ? 1u : 0u) << k;
        float w = v ? 1.0f : 0.0f;
        accx += cax[k] * w; accy += cay[k] * w;
        px[k] = cax[k]; py[k] = cay[k];
        sxc[k * 64 + lane] = cax[k];
        syc[k * 64 + lane] = cay[k];
    }
    // B corners vs A (slots 4..7)
#pragma unroll
    for (int k = 0; k < 4; ++k) {
        float relx = cbx[k] - ax, rely = cby[k] - ay;
        float rx = relx * ca + rely * sa;
        float ry = -relx * sa + rely * ca;
        bool v = (fabsf(rx) <= adx * 0.5f + 1e-5f) &&
                 (fabsf(ry) <= ady * 0.5f + 1e-5f);
        vm |= (v ? 1u : 0u) << (4 + k);
        float w = v ? 1.0f : 0.0f;
        accx += cbx[k] * w; accy += cby[k] * w;
        px[4 + k] = cbx[k]; py[4 + k] = cby[k];
        sxc[(4 + k) * 64 + lane] = cbx[k];
        syc[(4 + k) * 64 + lane] = cby[k];
    }
    // edge intersections (slots 8..23)
#pragma unroll
    for (int a = 0; a < 4; ++a) {
        int a2 = (a + 1) & 3;
        float p1x = cax[a], p1y = cay[a];
        float d1x = cax[a2] - p1x, d1y = cay[a2] - p1y;
#pragma unroll
        for (int b = 0; b < 4; ++b) {
            int b2 = (b + 1) & 3;
            float q1x = cbx[b], q1y = cby[b];
            float d2x = cbx[b2] - q1x, d2y = cby[b2] - q1y;
            float denom = d1x * d2y - d1y * d2x;
            bool dok = fabsf(denom) > EPS;
            float safe = dok ? denom : 1.0f;
            float inv = __builtin_amdgcn_rcpf(safe);
            float dqx = q1x - p1x, dqy = q1y - p1y;
            float t = (dqx * d2y - dqy * d2x) * inv;
            float u = (dqx * d1y - dqy * d1x) * inv;
            bool v = dok && (t >= 0.0f) && (t <= 1.0f) && (u >= 0.0f) && (u <= 1.0f);
            int o = 8 + a * 4 + b;
            float ipx = p1x + t * d1x;
            float ipy = p1y + t * d1y;
            vm |= (v ? 1u : 0u) << o;
            float w = v ? 1.0f : 0.0f;
            accx += ipx * w; accy += ipy * w;
            px[o] = ipx; py[o] = ipy;
            sxc[o * 64 + lane] = ipx;
            syc[o * 64 + lane] = ipy;
        }
    }

    int cnt = __popc(vm);
    float cntf = (float)(cnt > 1 ? cnt : 1);
    float cx_ = accx / cntf, cy_ = accy / cntf;

    unsigned key[NPTS];
#pragma unroll
    for (int k = 0; k < NPTS; ++k) {
        float rx = px[k] - cx_, ry = py[k] - cy_;    // registers, no LDS wait
        float axx = fabsf(rx), ayy = fabsf(ry);
        float d = fmaxf(axx + ayy, 1e-30f);
        float r = ry * __builtin_amdgcn_rcpf(d);
        float t = (rx >= 0.0f) ? r : ((ry >= 0.0f) ? 2.0f - r : -2.0f - r);
        unsigned u = __float_as_uint(t);
        unsigned ordered = u ^ ((unsigned)((int)u >> 31) | 0x80000000u);
        bool v = (vm >> k) & 1u;
        key[k] = v ? ((ordered & 0xFFFFFFE0u) | (unsigned)k)
                   : (0xFFFFFF00u | (unsigned)k);
    }
    // px/py dead here -> register pressure drops before the sort

    sort_net(key);

    // sorted walk: gather each lane's own columns by embedded slot index
    float s = 0.0f, x0 = 0.0f, y0 = 0.0f;
    float prevx = 0.0f, prevy = 0.0f, lastx = 0.0f, lasty = 0.0f;
#pragma unroll
    for (int r = 0; r < NPTS; ++r) {
        int j = (int)(key[r] & 31u);               // slot < 24 by construction
        float xr = sxc[j * 64 + lane];
        float yr = syc[j * 64 + lane];
        if (r == 0) { x0 = xr; y0 = yr; }
        else s += (r < cnt) ? (prevx * yr - xr * prevy) : 0.0f;
        bool isLast = (r == cnt - 1);
        lastx = isLast ? xr : lastx;
        lasty = isLast ? yr : lasty;
        prevx = xr; prevy = yr;
    }
    s += (cnt >= 1) ? (lastx * y0 - x0 * lasty) : 0.0f;

    float area = 0.5f * fabsf(s);
    return (cnt >= 3) ? area : 0.0f;
}

// ---- register-array heavy path (fallback kernels only) ----
__device__ __forceinline__ float pair_area(const float* __restrict__ A,
                                           const float* __restrict__ B)
{
    float ax = A[0], ay = A[1], adx = A[3], ady = A[4], ayaw = A[6];
    float bx = B[0], by = B[1], bdx = B[3], bdy = B[4], byaw = B[6];

    float ca = __builtin_cosf(ayaw), sa = __builtin_sinf(ayaw);
    float cb = __builtin_cosf(byaw), sb = __builtin_sinf(byaw);

    const float tx[4] = {0.5f, 0.5f, -0.5f, -0.5f};
    const float ty[4] = {0.5f, -0.5f, -0.5f, 0.5f};

    float cax[4], cay[4], cbx[4], cby[4];
#pragma unroll
    for (int k = 0; k < 4; ++k) {
        float lx = tx[k] * adx, ly = ty[k] * ady;
        cax[k] = lx * ca - ly * sa + ax;
        cay[k] = lx * sa + ly * ca + ay;
        lx = tx[k] * bdx; ly = ty[k] * bdy;
        cbx[k] = lx * cb - ly * sb + bx;
        cby[k] = lx * sb + ly * cb + by;
    }

    float px[NPTS], py[NPTS];
    bool valid[NPTS];

#pragma unroll
    for (int k = 0; k < 4; ++k) {
        float relx = cax[k] - bx, rely = cay[k] - by;
        float rx = relx * cb + rely * sb;
        float ry = -relx * sb + rely * cb;
        valid[k] = (fabsf(rx) <= bdx * 0.5f + 1e-5f) &&
                   (fabsf(ry) <= bdy * 0.5f + 1e-5f);
        px[k] = cax[k]; py[k] = cay[k];
    }
#pragma unroll
    for (int k = 0; k < 4; ++k) {
        float relx = cbx[k] - ax, rely = cby[k] - ay;
        float rx = relx * ca + rely * sa;
        float ry = -relx * sa + rely * ca;
        valid[4 + k] = (fabsf(rx) <= adx * 0.5f + 1e-5f) &&
                       (fabsf(ry) <= ady * 0.5f + 1e-5f);
        px[4 + k] = cbx[k]; py[4 + k] = cby[k];
    }

#pragma unroll
    for (int a = 0; a < 4; ++a) {
        int a2 = (a + 1) & 3;
        float p1x = cax[a], p1y = cay[a];
        float d1x = cax[a2] - p1x, d1y = cay[a2] - p1y;
#pragma unroll
        for (int b = 0; b < 4; ++b) {
            int b2 = (b + 1) & 3;
            float q1x = cbx[b], q1y = cby[b];
            float d2x = cbx[b2] - q1x, d2y = cby[b2] - q1y;
            float denom = d1x * d2y - d1y * d2x;
            bool dok = fabsf(denom) > EPS;
            float safe = dok ? denom : 1.0f;
            float inv = __builtin_amdgcn_rcpf(safe);
            float dqx = q1x - p1x, dqy = q1y - p1y;
            float t = (dqx * d2y - dqy * d2x) * inv;
            float u = (dqx * d1y - dqy * d1x) * inv;
            bool v = dok && (t >= 0.0f) && (t <= 1.0f) && (u >= 0.0f) && (u <= 1.0f);
            int o = 8 + a * 4 + b;
            px[o] = p1x + t * d1x;
            py[o] = p1y + t * d1y;
            valid[o] = v;
        }
    }

    int cnt = 0;
    float sx = 0.0f, sy = 0.0f;
#pragma unroll
    for (int k = 0; k < NPTS; ++k) {
        if (valid[k]) cnt++;
        float w = valid[k] ? 1.0f : 0.0f;
        sx += px[k] * w;
        sy += py[k] * w;
    }
    float cntf = (float)(cnt > 1 ? cnt : 1);
    float cx_ = sx / cntf, cy_ = sy / cntf;

    unsigned key[NPTS];
#pragma unroll
    for (int k = 0; k < NPTS; ++k) {
        float rx = px[k] - cx_, ry = py[k] - cy_;
        float axx = fabsf(rx), ayy = fabsf(ry);
        float d = fmaxf(axx + ayy, 1e-30f);
        float r = ry * __builtin_amdgcn_rcpf(d);
        float t = (rx >= 0.0f) ? r : ((ry >= 0.0f) ? 2.0f - r : -2.0f - r);
        unsigned u = __float_as_uint(t);
        unsigned ordered = u ^ ((unsigned)((int)u >> 31) | 0x80000000u);
        key[k] = valid[k] ? ((ordered & 0xFFFFFFE0u) | (unsigned)k)
                          : (0xFFFFFF00u | (unsigned)k);
    }

#pragma unroll
    for (int c = 0; c < NET.n; ++c) {
        int lo = NET.lo[c], hi = NET.hi[c];
        bool sw = key[hi] < key[lo];
        unsigned kl = key[lo], kh = key[hi];
        float xl = px[lo], xh = px[hi];
        float yl = py[lo], yh = py[hi];
        key[lo] = sw ? kh : kl;  key[hi] = sw ? kl : kh;
        px[lo]  = sw ? xh : xl;  px[hi]  = sw ? xl : xh;
        py[lo]  = sw ? yh : yl;  py[hi]  = sw ? yl : yh;
    }

    float lastx = 0.0f, lasty = 0.0f;
#pragma unroll
    for (int r = 0; r < NPTS; ++r) {
        bool isLast = (r == cnt - 1);
        lastx = isLast ? px[r] : lastx;
        lasty = isLast ? py[r] : lasty;
    }

    float s = 0.0f;
#pragma unroll
    for (int r = 0; r + 1 < NPTS; ++r) {
        float cr = px[r] * py[r + 1] - px[r + 1] * py[r];
        s += (r + 1 < cnt) ? cr : 0.0f;
    }
    s += (cnt >= 1) ? (lastx * py[0] - px[0] * lasty) : 0.0f;

    float area = 0.5f * fabsf(s);
    return (cnt >= 3) ? area : 0.0f;
}

// ============================================================================
// Row-pair kernel — R12 shell unchanged (proven 15.9us): ROWS=2, 500x512,
// chunked coalesced staging, dual-row cull, owner-wave phase 2 with chunk-
// aliased scratch, waves_per_eu(4,4) for the 128-VGPR budget.
// ============================================================================
__global__ __launch_bounds__(512)
__attribute__((amdgpu_waves_per_eu(4, 4)))
void rowpair_kernel(
    const float* __restrict__ boxes, float* __restrict__ out, int m, int n)
{
    __shared__ __align__(16) float chunk[CHUNKB * 7];      // 28KB raw boxes
    __shared__ unsigned short wl[ROWS * MAXN_LDS];         // packed (rl<<12|j)
    __shared__ unsigned lcnt;

    const int i0   = blockIdx.x * ROWS;
    const int tid  = threadIdx.x;
    const int wv   = tid >> 6;            // 0..7
    const int lane = tid & 63;

    if (tid == 0) lcnt = 0;

    // ---- i-boxes for both rows (broadcast loads) ----
    float xi[ROWS], yi[ROWS], ri[ROWS];
    bool rowok[ROWS];
#pragma unroll
    for (int rl = 0; rl < ROWS; ++rl) {
        int i = i0 + rl;
        rowok[rl] = (i < m);
        int ic = rowok[rl] ? i : (m - 1);
        const float* b = boxes + (size_t)ic * 7;
        float dx = b[3], dy = b[4];
        xi[rl] = b[0]; yi[rl] = b[1];
        ri[rl] = 0.5f * sqrtf(dx * dx + dy * dy) + 0.005f;
    }

    const unsigned long long below = (1ull << lane) - 1ull;

    // ---- chunked stage + dual-row cull ----
    for (int c0 = 0; c0 < n; c0 += CHUNKB) {
        int cb = n - c0; if (cb > CHUNKB) cb = CHUNKB;
        int words = cb * 7;
        const float* src = boxes + (size_t)(m + c0) * 7;

        if ((((size_t)src) & 15) == 0) {
            int n4 = words >> 2;
            const float4* s4 = (const float4*)src;
            float4* d4 = (float4*)chunk;
            for (int t = tid; t < n4; t += 512) d4[t] = s4[t];
            for (int t = (n4 << 2) + tid; t < words; t += 512)
                chunk[t] = src[t];
        } else {
            for (int t = tid; t < words; t += 512) chunk[t] = src[t];
        }
        __syncthreads();   // chunk ready (1st iter also publishes lcnt=0)

        for (int tt = tid; tt < cb; tt += 512) {
            int j = c0 + tt;
            const float* bj = &chunk[tt * 7];      // stride-7: 2-way, free
            float xj = bj[0], yj = bj[1];
            float dxj = bj[3], dyj = bj[4];
            float rj = 0.5f * sqrtf(dxj * dxj + dyj * dyj) + 0.005f;

#pragma unroll
            for (int rl = 0; rl < ROWS; ++rl) {
                bool keep = false;
                if (rowok[rl]) {
                    float ddx = xi[rl] - xj, ddy = yi[rl] - yj;
                    float rr = ri[rl] + rj;
                    keep = (ddx * ddx + ddy * ddy) <= rr * rr;
                    if (!keep) out[(size_t)(i0 + rl) * n + j] = 0.0f;
                }
                unsigned long long mask = __ballot(keep);
                int c = __popcll(mask);
                if (c > 0) {
                    int lead = __ffsll(mask) - 1;
                    unsigned base = 0;
                    if (lane == lead) base = atomicAdd(&lcnt, (unsigned)c);
                    base = (unsigned)__shfl((int)base, lead, 64);
                    if (keep) {
                        int rank = __popcll(mask & below);
                        wl[base + rank] =
                            (unsigned short)(((unsigned)rl << 12) | (unsigned)j);
                    }
                }
            }
        }
        __syncthreads();   // chunk consumed; safe to overwrite next iter
    }

    // ---- phase 2: owner wave processes all survivors; chunk is dead ->
    //      its first 12KB serve as the owner wave's point-column scratch ----
    unsigned cnt = lcnt;
    if (wv == (int)(blockIdx.x & 7u)) {
        float* scr = chunk;                    // 12KB needed, 28KB available
        for (unsigned base = 0; base < cnt; base += 64) {
            unsigned t = base + (unsigned)lane;
            if (t < cnt) {
                unsigned e = wl[t];
                int rl = (int)(e >> 12);
                int j  = (int)(e & 0xFFFu);
                int i  = i0 + rl;
                out[(size_t)i * n + j] =
                    pair_area_lds(boxes + (size_t)i * 7,
                                  boxes + (size_t)(m + j) * 7, scr, lane);
            }
        }
    }
}

// ============================================================================
// Fallback pipeline — unchanged (only for odd shapes).
// ============================================================================
__global__ __launch_bounds__(256) void prep_kernel(
    const float* __restrict__ boxes, float* __restrict__ xs,
    float* __restrict__ ys, float* __restrict__ rs,
    unsigned* __restrict__ counters, int total)
{
    int t = blockIdx.x * blockDim.x + threadIdx.x;
    if (t < NREG * CTR_STRIDE) counters[t] = 0;
    if (t < total) {
        float dx = boxes[(size_t)t * 7 + 3];
        float dy = boxes[(size_t)t * 7 + 4];
        xs[t] = boxes[(size_t)t * 7 + 0];
        ys[t] = boxes[(size_t)t * 7 + 1];
        rs[t] = 0.5f * sqrtf(dx * dx + dy * dy) + 0.005f;
    }
}

__global__ __launch_bounds__(256) void cull_kernel(
    const float* __restrict__ xs, const float* __restrict__ ys,
    const float* __restrict__ rs, float* __restrict__ out,
    unsigned* __restrict__ counters, unsigned* __restrict__ regions,
    int m, int n, unsigned reg_cap)
{
    int jb = blockIdx.x, i = blockIdx.y;
    int tid = threadIdx.x;
    int j = jb * 256 + tid;

    bool keep = false;
    if (j < n) {
        float dx = xs[i] - xs[m + j];
        float dy = ys[i] - ys[m + j];
        float rr = rs[i] + rs[m + j];
        keep = (dx * dx + dy * dy) <= rr * rr;
        out[(size_t)i * n + j] = 0.0f;
    }

    unsigned long long mask = __ballot(keep);
    if (mask == 0ull) return;

    int lane = tid & 63;
    unsigned gwid = ((unsigned)(i * gridDim.x + jb) << 2) | ((unsigned)tid >> 6);
    unsigned region = gwid & (NREG - 1);

    int c = __popcll(mask);
    int lead = __ffsll((unsigned long long)mask) - 1;
    unsigned pos = 0;
    if (lane == lead) pos = atomicAdd(&counters[region * CTR_STRIDE], (unsigned)c);
    pos = (unsigned)__shfl((int)pos, lead, 64);
    if (keep) {
        int rank = __popcll(mask & ((1ull << lane) - 1ull));
        regions[(size_t)region * reg_cap + pos + rank] =
            ((unsigned)i << 12) | (unsigned)j;
    }
}

__global__ __launch_bounds__(64) void process_kernel(
    const float* __restrict__ boxes, float* __restrict__ out,
    const unsigned* __restrict__ counters, const unsigned* __restrict__ regions,
    int m, int n, unsigned reg_cap)
{
    unsigned region = blockIdx.x >> 2;
    unsigned cnt = counters[region * CTR_STRIDE];
    const unsigned* seg = regions + (size_t)region * reg_cap;
    for (unsigned t = ((blockIdx.x & 3u) << 6) | threadIdx.x; t < cnt; t += 256) {
        unsigned v = seg[t];
        int i = (int)(v >> 12);
        int j = (int)(v & 4095u);
        const float* A = boxes + (size_t)i * 7;
        const float* B = boxes + (size_t)(m + j) * 7;
        out[(size_t)i * n + j] = pair_area(A, B);
    }
}

__global__ __launch_bounds__(256) void overlap_kernel(
    const float* __restrict__ boxes, float* __restrict__ out, int m, int n)
{
    int j = blockIdx.x * blockDim.x + threadIdx.x;
    int i = blockIdx.y;
    if (j >= n) return;
    const float* A = boxes + (size_t)i * 7;
    const float* B = boxes + (size_t)(m + j) * 7;
    out[(size_t)i * n + j] = pair_area(A, B);
}

extern "C" void kernel_launch(void* const* d_in, const int* in_sizes, int n_in,
                              void* d_out, int out_size, void* d_ws, size_t ws_size,
                              hipStream_t stream) {
    const float* boxes = (const float*)d_in[0];
    float* out = (float*)d_out;
    int total = in_sizes[0] / 7;   // 3000 boxes
    int m = total / 3;             // 1000
    int n = total - m;             // 2000

    // ---------------- single-dispatch row-pair kernel ----------------
    if (n > 0 && n <= MAXN_LDS && m >= 1) {
        int nb = (m + ROWS - 1) / ROWS;
        hipLaunchKernelGGL(rowpair_kernel, dim3((unsigned)nb), dim3(512),
                           0, stream, boxes, out, m, n);
        return;
    }

    // ---------------- fallback: verified 3-kernel pipeline ----------------
    int bpr = (n + 255) / 256;
    unsigned total_waves = (unsigned)(bpr * m) * 4u;
    unsigned reg_cap = ((total_waves + NREG - 1) / NREG) * 64u;

    size_t ctr_off = 0;
    size_t xs_off  = ctr_off + (size_t)NREG * CTR_STRIDE * 4;
    size_t ys_off  = xs_off + (size_t)total * 4;
    size_t rs_off  = ys_off + (size_t)total * 4;
    size_t reg_off = ((rs_off + (size_t)total * 4) + 255) & ~(size_t)255;
    size_t need    = reg_off + (size_t)NREG * reg_cap * 4;

    if (ws_size < need || n > 4095) {
        dim3 block(256, 1, 1);
        dim3 grid((n + 255) / 256, m, 1);
        hipLaunchKernelGGL(overlap_kernel, grid, block, 0, stream, boxes, out, m, n);
        return;
    }

    unsigned* counters = (unsigned*)((char*)d_ws + ctr_off);
    float* xs = (float*)((char*)d_ws + xs_off);
    float* ys = (float*)((char*)d_ws + ys_off);
    float* rs = (float*)((char*)d_ws + rs_off);
    unsigned* regions = (unsigned*)((char*)d_ws + reg_off);

    int prep_threads = (NREG * CTR_STRIDE > total) ? NREG * CTR_STRIDE : total;
    hipLaunchKernelGGL(prep_kernel, dim3((prep_threads + 255) / 256), dim3(256),
                       0, stream, boxes, xs, ys, rs, counters, total);

    hipLaunchKernelGGL(cull_kernel, dim3(bpr, m, 1), dim3(256), 0, stream,
                       xs, ys, rs, out, counters, regions, m, n, reg_cap);

    hipLaunchKernelGGL(process_kernel, dim3(NREG * 4, 1, 1), dim3(64), 0, stream,
                       boxes, out, counters, regions, m, n, reg_cap);
}